// Round 8
// baseline (1088.332 us; speedup 1.0000x reference)
//
#include <hip/hip_runtime.h>

// Orient_Conv: 3x3 orientation-gated conv, 4 orientations + per-pixel argmax.
// B=4, CIN=COUT=32, H=W=128, pad=1.
//
// Gate identity (C=cos(wr), S=sin(wr), r0=cos(th), r1=sin(th)):
//   u = C*r0+S*r1, v = C*r1-S*r0
//   gates: o0=relu(u), o1=relu(v), o2=relu(-u)=relu(u)-u, o3=relu(v)-v
// Rotated weights at tap (i,j): w0=w[i][j], w1=w[2-j][i], w2=w[2-i][2-j],
//   w3=w[j][2-i].
//
// R7 = R5 core + 2 output rows per block (amortizes staging/LDS/weights/
// barriers over 2x pixels) + split coalesced weight tables:
//   tab4[cc][tap][oc] = {C,S,w0,w1}  (lane-stride 16B -> 512B/wave, imm offs)
//   tab2[cc][tap][oc] = {w2,w3}
// Staged row r serves out-row0 tap-row r (r<3) and out-row1 tap-row r-1 (r>0);
// weight row loaded once at r, reused at r+1. LDS plane stride 2180 (!%32)
// for 0 bank conflicts. Scalar fp32 core: 16 VALU ops/elem = 123 us floor.
// Block 512 = 32oc x 16pxg; thread = 4px x 2rows x 1oc. Grid 512.

#define B_    4
#define CIN_  32
#define COUT_ 32
#define H_    128
#define W_    128
#define HW_   (H_ * W_)
#define OUTSZ_ (B_ * COUT_ * H_ * W_)

// tab4: 9216 float4 (147456 B) at ws+0 ; tab2: 9216 float2 at ws+147456
__global__ __launch_bounds__(256)
void build_wtab(const float* __restrict__ w, const float* __restrict__ wr,
                float4* __restrict__ tab4, float2* __restrict__ tab2)
{
    int idx = blockIdx.x * 256 + threadIdx.x;   // ((cc*9+tap)<<5)|oc
    if (idx >= CIN_ * 9 * COUT_) return;        // 9216
    int oc  = idx & 31;
    int t2  = idx >> 5;
    int tap = t2 % 9;
    int cc  = t2 / 9;
    int i = tap / 3, j = tap - i * 3;
    int base = (oc * CIN_ + cc) * 9;
    float w0 = w[base + i * 3 + j];
    float w1 = w[base + (2 - j) * 3 + i];
    float w2 = w[base + (2 - i) * 3 + (2 - j)];
    float w3 = w[base + j * 3 + (2 - i)];
    float S, C;
    sincosf(wr[base + i * 3 + j], &S, &C);
    tab4[idx] = make_float4(C, S, w0, w1);
    tab2[idx] = make_float2(w2, w3);
}

#define NC_    8                      // channels staged per barrier-pair
#define NG_    (CIN_ / NC_)           // 4 groups
#define RSTR_  68                     // col stride (66 used)
#define CLSTR_ (4 * RSTR_)            // 272 floats per staged channel (4 rows)
#define USED_  (NC_ * CLSTR_)         // 2176 slots per plane
#define ASTR_  2180                   // plane stride (2180 % 32 = 4 != 0)

// 16-op scalar core applied to one accumulator row
#define BODY(ACC, W4, W2, FV, R0V, R1V)                                   \
    {                                                                     \
        float u  = fmaf((W4).x, (R0V), (W4).y * (R1V));                   \
        float vv = fmaf((W4).x, (R1V), -((W4).y * (R0V)));                \
        float g0 = fmaxf(u, 0.0f);                                        \
        float g1 = fmaxf(vv, 0.0f);                                       \
        float g2 = g0 - u;                                                \
        float g3 = g1 - vv;                                               \
        (ACC)[0] = fmaf((FV) * g0, (W4).z, (ACC)[0]);                     \
        (ACC)[1] = fmaf((FV) * g1, (W4).w, (ACC)[1]);                     \
        (ACC)[2] = fmaf((FV) * g2, (W2).x, (ACC)[2]);                     \
        (ACC)[3] = fmaf((FV) * g3, (W2).y, (ACC)[3]);                     \
    }

__global__ __launch_bounds__(512, 4)
void orient_conv_kernel(const float* __restrict__ f,
                        const float* __restrict__ r0,
                        const float* __restrict__ r1,
                        const float4* __restrict__ tab4,
                        const float2* __restrict__ tab2,
                        float* __restrict__ out)
{
    // planes: sm[0]=f, sm[ASTR_]=r0, sm[2*ASTR_]=r1; each [cl(8)][row(4)][col(68)]
    __shared__ float sm[3 * ASTR_];    // 26160 B

    const int tid   = threadIdx.x;
    const int oc    = tid & 31;
    const int pxg   = tid >> 5;            // 0..15
    const int px0   = pxg << 2;            // 4 px per thread
    const int bid   = blockIdx.x;          // 0..511
    const int b     = bid >> 7;
    const int rem   = bid & 127;
    const int h0    = (rem >> 1) << 1;     // even output row; rows h0, h0+1
    const int wbase = (rem & 1) << 6;      // 0 or 64

    // ---- staging descriptors: 5 rounds (slot = tid + 512k, valid < 2176) ----
    int      goff[5], sidx[5];
    unsigned msk[5];
#pragma unroll
    for (int k = 0; k < 5; ++k) {
        int s = tid + (k << 9);
        if (s < USED_) {
            int cl  = s / CLSTR_;
            int rr  = s - cl * CLSTR_;
            int row = rr / RSTR_;
            int col = rr - row * RSTR_;
            int gh = h0 + row - 1;          // -1 .. 128
            int gw = wbase + col - 1;
            bool ok = (col < 66) & ((unsigned)gh < (unsigned)H_) &
                      ((unsigned)gw < (unsigned)W_);
            goff[k] = ok ? (cl * HW_ + gh * W_ + gw) : 0;
            msk[k]  = ok ? 0xFFFFFFFFu : 0u;
            sidx[k] = s;
        } else { goff[k] = 0; msk[k] = 0u; sidx[k] = USED_; }  // USED_<ASTR_ pad
    }
    const int chanBase = b * (CIN_ * HW_);

    float acc[2][4][4];                    // [row][px][orient]
#pragma unroll
    for (int rr = 0; rr < 2; ++rr)
#pragma unroll
        for (int p = 0; p < 4; ++p)
#pragma unroll
            for (int o = 0; o < 4; ++o) acc[rr][p][o] = 0.0f;

    // ---- prefetch group 0 ----
    float tF[5], tA[5], tB[5];
    {
        const float* fb = f  + chanBase;
        const float* ab = r0 + chanBase;
        const float* bb = r1 + chanBase;
#pragma unroll
        for (int k = 0; k < 5; ++k) {
            tF[k] = fb[goff[k]]; tA[k] = ab[goff[k]]; tB[k] = bb[goff[k]];
        }
    }

#pragma unroll 1
    for (int g = 0; g < NG_; ++g) {
        __syncthreads();   // all waves done reading LDS of group g-1
#pragma unroll
        for (int k = 0; k < 5; ++k) {
            sm[            sidx[k]] = __uint_as_float(__float_as_uint(tF[k]) & msk[k]);
            sm[ASTR_     + sidx[k]] = __uint_as_float(__float_as_uint(tA[k]) & msk[k]);
            sm[2 * ASTR_ + sidx[k]] = __uint_as_float(__float_as_uint(tB[k]) & msk[k]);
        }
        __syncthreads();

        // ---- prefetch group g+1 (in flight during compute below) ----
        if (g + 1 < NG_) {
            const int gb = chanBase + (g + 1) * (NC_ * HW_);
            const float* fb = f  + gb;
            const float* ab = r0 + gb;
            const float* bb = r1 + gb;
#pragma unroll
            for (int k = 0; k < 5; ++k) {
                tF[k] = fb[goff[k]]; tA[k] = ab[goff[k]]; tB[k] = bb[goff[k]];
            }
        }

        // ---- compute the NC_ staged channels ----
#pragma unroll 1
        for (int cl = 0; cl < NC_; ++cl) {
            const int cc = g * NC_ + cl;
            // imm-offset bases: tap t at (t-4)*512B (tab4) / t*256B (tab2)
            const float4* w4 = tab4 + (((cc * 9 + 4) << 5) | oc);
            const float2* w2 = tab2 + (((cc * 9) << 5) | oc);

            float4 c4_0, c4_1, c4_2, p4_0, p4_1, p4_2;
            float2 c2_0, c2_1, c2_2, p2_0, p2_1, p2_2;
#pragma unroll
            for (int r = 0; r < 4; ++r) {
                const int bi = cl * CLSTR_ + r * RSTR_ + px0;
                float4 F4 = *reinterpret_cast<const float4*>(&sm[bi]);
                float2 F2 = *reinterpret_cast<const float2*>(&sm[bi + 4]);
                float4 A4 = *reinterpret_cast<const float4*>(&sm[ASTR_ + bi]);
                float2 A2 = *reinterpret_cast<const float2*>(&sm[ASTR_ + bi + 4]);
                float4 B4 = *reinterpret_cast<const float4*>(&sm[2 * ASTR_ + bi]);
                float2 B2 = *reinterpret_cast<const float2*>(&sm[2 * ASTR_ + bi + 4]);
                const float fin[6]  = {F4.x, F4.y, F4.z, F4.w, F2.x, F2.y};
                const float ain[6]  = {A4.x, A4.y, A4.z, A4.w, A2.x, A2.y};
                const float bin_[6] = {B4.x, B4.y, B4.z, B4.w, B2.x, B2.y};

                if (r < 3) {            // load weight row r (taps r*3+{0,1,2})
                    c4_0 = w4[(r * 3 + 0 - 4) * 32];
                    c4_1 = w4[(r * 3 + 1 - 4) * 32];
                    c4_2 = w4[(r * 3 + 2 - 4) * 32];
                    c2_0 = w2[(r * 3 + 0) * 32];
                    c2_1 = w2[(r * 3 + 1) * 32];
                    c2_2 = w2[(r * 3 + 2) * 32];
                }
#pragma unroll
                for (int p = 0; p < 4; ++p) {
                    const float fv  = fin [p];
                    const float av  = ain [p];
                    const float bv  = bin_[p];
                    if (r < 3) BODY(acc[0][p], c4_0, c2_0, fv, av, bv);
                    if (r > 0) BODY(acc[1][p], p4_0, p2_0, fv, av, bv);
                    const float fv1  = fin [p + 1];
                    const float av1  = ain [p + 1];
                    const float bv1  = bin_[p + 1];
                    if (r < 3) BODY(acc[0][p], c4_1, c2_1, fv1, av1, bv1);
                    if (r > 0) BODY(acc[1][p], p4_1, p2_1, fv1, av1, bv1);
                    const float fv2  = fin [p + 2];
                    const float av2  = ain [p + 2];
                    const float bv2  = bin_[p + 2];
                    if (r < 3) BODY(acc[0][p], c4_2, c2_2, fv2, av2, bv2);
                    if (r > 0) BODY(acc[1][p], p4_2, p2_2, fv2, av2, bv2);
                }
                p4_0 = c4_0; p4_1 = c4_1; p4_2 = c4_2;
                p2_0 = c2_0; p2_1 = c2_1; p2_2 = c2_2;
            }
        }
    }

    // ---- epilogue: max/argmax over orientations (first-max tie-break) ----
    const float cosv[4] = {1.0f, -4.37113883e-08f, -1.0f, 1.19248806e-08f};
    const float sinv[4] = {0.0f, 1.0f, -8.74227766e-08f, -1.0f};
#pragma unroll
    for (int rr = 0; rr < 2; ++rr) {
#pragma unroll
        for (int p = 0; p < 4; ++p) {
            int wcol = wbase + px0 + p;
            float a0 = acc[rr][p][0], a1 = acc[rr][p][1];
            float a2 = acc[rr][p][2], a3 = acc[rr][p][3];
            float best = a0; int bi = 0;
            if (a1 > best) { best = a1; bi = 1; }
            if (a2 > best) { best = a2; bi = 2; }
            if (a3 > best) { best = a3; bi = 3; }
            size_t o = ((size_t)(b * COUT_ + oc) * H_ + (h0 + rr)) * W_ + wcol;
            out[o]              = best;
            out[o + OUTSZ_]     = cosv[bi];
            out[o + 2 * OUTSZ_] = sinv[bi];
        }
    }
}

extern "C" void kernel_launch(void* const* d_in, const int* in_sizes, int n_in,
                              void* d_out, int out_size, void* d_ws, size_t ws_size,
                              hipStream_t stream)
{
    const float* f  = (const float*)d_in[0];
    const float* r0 = (const float*)d_in[1];
    const float* r1 = (const float*)d_in[2];
    const float* w  = (const float*)d_in[3];
    const float* wr = (const float*)d_in[4];
    float* out = (float*)d_out;
    float4* tab4 = (float4*)d_ws;                         // 147456 B
    float2* tab2 = (float2*)((char*)d_ws + 147456);       //  73728 B

    build_wtab<<<dim3(36), dim3(256), 0, stream>>>(w, wr, tab4, tab2);
    orient_conv_kernel<<<dim3(B_ * H_), dim3(512), 0, stream>>>(
        f, r0, r1, tab4, tab2, out);
}

// Round 9
// 314.581 us; speedup vs baseline: 3.4596x; 3.4596x over previous
//
#include <hip/hip_runtime.h>

// Orient_Conv: 3x3 orientation-gated conv, 4 orientations + per-pixel argmax.
// B=4, CIN=COUT=32, H=W=128, pad=1.
//
// Gate identity (C=cos(wr), S=sin(wr), r0=cos(th), r1=sin(th)):
//   u = C*r0+S*r1, v = C*r1-S*r0
//   gates: o0=relu(u), o1=relu(v), o2=relu(-u)=relu(u)-u, o3=relu(v)-v
// Rotated weights at tap (i,j): w0=w[i][j], w1=w[2-j][i], w2=w[2-i][2-j],
//   w3=w[j][2-i].
//
// R8 = R5 inner core (scalar fp32, 16 VALU ops/elem = 123 us floor; weight
// table [cc][tap][oc][8] -> coalesced 1KB wave loads, L1-friendly) with
// occupancy restructure: block 256 (32oc x 8pxg, 4px/thr -> same ~60 VGPR),
// grid 2048 -> 8 blocks/CU capacity, 4-wave barriers, spare blocks hide
// stalls (R5: exact-fit 4/CU, 41% occupancy, 28% idle).
// R6's regression was its [cc][oc][tap] weight layout (L1 thrash), not the
// smaller block. R4/R7 lesson: keep per-thread state ~60 VGPR, no 2-row or
// register-pipelined variants (spill -> GB of scratch).

#define B_    4
#define CIN_  32
#define COUT_ 32
#define H_    128
#define W_    128
#define HW_   (H_ * W_)
#define OUTSZ_ (B_ * COUT_ * H_ * W_)

// tab layout: [cc][tap][oc][8] = {C,S,w0,w1,w2,w3,0,0}; 294912 B
__global__ __launch_bounds__(256)
void build_wtab(const float* __restrict__ w, const float* __restrict__ wr,
                float* __restrict__ tab)
{
    int idx = blockIdx.x * 256 + threadIdx.x;   // ((cc*9+tap)<<5)|oc
    if (idx >= CIN_ * 9 * COUT_) return;        // 9216
    int oc  = idx & 31;
    int t2  = idx >> 5;
    int tap = t2 % 9;
    int cc  = t2 / 9;
    int i = tap / 3, j = tap - i * 3;
    int base = (oc * CIN_ + cc) * 9;
    float w0 = w[base + i * 3 + j];
    float w1 = w[base + (2 - j) * 3 + i];
    float w2 = w[base + (2 - i) * 3 + (2 - j)];
    float w3 = w[base + j * 3 + (2 - i)];
    float S, C;
    sincosf(wr[base + i * 3 + j], &S, &C);
    float* dst = tab + (size_t)idx * 8;
    dst[0] = C;  dst[1] = S;
    dst[2] = w0; dst[3] = w1;
    dst[4] = w2; dst[5] = w3;
    dst[6] = 0.0f; dst[7] = 0.0f;
}

#define NC_    8                      // channels staged per barrier-pair
#define NG_    (CIN_ / NC_)           // 4 groups
#define RSTR_  36                     // padded col stride (34 used)
#define CLSTR_ (3 * RSTR_)            // 108 floats per staged channel
#define ASZ_   (NC_ * CLSTR_)         // 864 floats per plane
#define USED_  (NC_ * 3 * 34)         // 816 used slots per plane

__global__ __launch_bounds__(256, 4)
void orient_conv_kernel(const float* __restrict__ f,
                        const float* __restrict__ r0,
                        const float* __restrict__ r1,
                        const float* __restrict__ tab,
                        float* __restrict__ out)
{
    __shared__ float sF[ASZ_], sR0[ASZ_], sR1[ASZ_];   // 10368 B total

    const int tid   = threadIdx.x;
    const int oc    = tid & 31;
    const int pxg   = tid >> 5;            // 0..7
    const int px0   = pxg << 2;            // 4 px per thread (0..28)
    const int bid   = blockIdx.x;          // 0..2047
    const int b     = bid >> 9;
    const int rem   = bid & 511;
    const int h     = rem >> 2;            // 0..127
    const int wbase = (rem & 3) << 5;      // 0,32,64,96

    // ---- staging descriptors: rounds 0..2 always valid, round 3 tid<48 ----
    int      goff[4], sidx[4];
    unsigned msk[4];
#pragma unroll
    for (int k = 0; k < 4; ++k) {
        int s = tid + (k << 8);
        if (s < USED_) {
            int cl  = s / 102;            // 3*34 slots per channel
            int r2  = s - cl * 102;
            int row = r2 / 34;
            int col = r2 - row * 34;
            int gh = h + row - 1;
            int gw = wbase + col - 1;
            bool ok = ((unsigned)gh < (unsigned)H_) & ((unsigned)gw < (unsigned)W_);
            goff[k] = ok ? (cl * HW_ + gh * W_ + gw) : 0;
            msk[k]  = ok ? 0xFFFFFFFFu : 0u;
            sidx[k] = cl * CLSTR_ + row * RSTR_ + col;
        } else { goff[k] = 0; msk[k] = 0u; sidx[k] = ASZ_ - 1; }
    }
    const bool have3 = (tid + 768) < USED_;   // tid < 48
    const int chanBase = b * (CIN_ * HW_);

    float acc[4][4];                       // [px][orient]
#pragma unroll
    for (int p = 0; p < 4; ++p)
#pragma unroll
        for (int o = 0; o < 4; ++o) acc[p][o] = 0.0f;

    // ---- prefetch group 0 ----
    float tF[4], tA[4], tB[4];
    {
        const float* fb = f  + chanBase;
        const float* ab = r0 + chanBase;
        const float* bb = r1 + chanBase;
#pragma unroll
        for (int k = 0; k < 3; ++k) {
            tF[k] = fb[goff[k]]; tA[k] = ab[goff[k]]; tB[k] = bb[goff[k]];
        }
        if (have3) { tF[3] = fb[goff[3]]; tA[3] = ab[goff[3]]; tB[3] = bb[goff[3]]; }
    }

#pragma unroll 1
    for (int g = 0; g < NG_; ++g) {
        __syncthreads();   // all waves done reading LDS of group g-1
#pragma unroll
        for (int k = 0; k < 3; ++k) {
            sF [sidx[k]] = __uint_as_float(__float_as_uint(tF[k]) & msk[k]);
            sR0[sidx[k]] = __uint_as_float(__float_as_uint(tA[k]) & msk[k]);
            sR1[sidx[k]] = __uint_as_float(__float_as_uint(tB[k]) & msk[k]);
        }
        if (have3) {
            sF [sidx[3]] = __uint_as_float(__float_as_uint(tF[3]) & msk[3]);
            sR0[sidx[3]] = __uint_as_float(__float_as_uint(tA[3]) & msk[3]);
            sR1[sidx[3]] = __uint_as_float(__float_as_uint(tB[3]) & msk[3]);
        }
        __syncthreads();

        // ---- prefetch group g+1 (in flight during compute below) ----
        if (g + 1 < NG_) {
            const int gb = chanBase + (g + 1) * (NC_ * HW_);
            const float* fb = f  + gb;
            const float* ab = r0 + gb;
            const float* bb = r1 + gb;
#pragma unroll
            for (int k = 0; k < 3; ++k) {
                tF[k] = fb[goff[k]]; tA[k] = ab[goff[k]]; tB[k] = bb[goff[k]];
            }
            if (have3) { tF[3] = fb[goff[3]]; tA[3] = ab[goff[3]]; tB[3] = bb[goff[3]]; }
        }

        // ---- compute the NC_ staged channels ----
#pragma unroll 1
        for (int cl = 0; cl < NC_; ++cl) {
            const int cc = g * NC_ + cl;
            // two imm-offset bases (tap anchors 2 and 6) keep all 18 weight
            // loads within signed-13-bit global imm offsets
            const float* wb0 = tab + ((size_t)((cc * 9 + 2) << 5) | (unsigned)oc * 1) * 8;
            const float* wb1 = wb0 + 4 * 256;    // anchor at tap 6
#pragma unroll
            for (int i = 0; i < 3; ++i) {
                const int bi = cl * CLSTR_ + i * RSTR_ + px0;
                float4 F4 = *reinterpret_cast<const float4*>(&sF [bi]);
                float2 F2 = *reinterpret_cast<const float2*>(&sF [bi + 4]);
                float4 A4 = *reinterpret_cast<const float4*>(&sR0[bi]);
                float2 A2 = *reinterpret_cast<const float2*>(&sR0[bi + 4]);
                float4 B4 = *reinterpret_cast<const float4*>(&sR1[bi]);
                float2 B2 = *reinterpret_cast<const float2*>(&sR1[bi + 4]);
                const float fin[6]  = {F4.x, F4.y, F4.z, F4.w, F2.x, F2.y};
                const float ain[6]  = {A4.x, A4.y, A4.z, A4.w, A2.x, A2.y};
                const float bin_[6] = {B4.x, B4.y, B4.z, B4.w, B2.x, B2.y};
#pragma unroll
                for (int j = 0; j < 3; ++j) {
                    const int tap = i * 3 + j;
                    const float* wp = (tap < 5) ? (wb0 + (tap - 2) * 256)
                                                : (wb1 + (tap - 6) * 256);
                    float4 W4 = *reinterpret_cast<const float4*>(wp);
                    float2 W2 = *reinterpret_cast<const float2*>(wp + 4);
                    const float C  = W4.x, S  = W4.y;
                    const float w0 = W4.z, w1 = W4.w;
                    const float w2 = W2.x, w3 = W2.y;
#pragma unroll
                    for (int p = 0; p < 4; ++p) {
                        const float fv  = fin [p + j];
                        const float r0v = ain [p + j];
                        const float r1v = bin_[p + j];
                        float u  = fmaf(C, r0v, S * r1v);
                        float vv = fmaf(C, r1v, -(S * r0v));
                        float g0 = fmaxf(u,  0.0f);
                        float g1 = fmaxf(vv, 0.0f);
                        float g2 = g0 - u;     // relu(-u), exact
                        float g3 = g1 - vv;    // relu(-v), exact
                        acc[p][0] = fmaf(fv * g0, w0, acc[p][0]);
                        acc[p][1] = fmaf(fv * g1, w1, acc[p][1]);
                        acc[p][2] = fmaf(fv * g2, w2, acc[p][2]);
                        acc[p][3] = fmaf(fv * g3, w3, acc[p][3]);
                    }
                }
            }
        }
    }

    // ---- epilogue: max/argmax over orientations (first-max tie-break) ----
    const float cosv[4] = {1.0f, -4.37113883e-08f, -1.0f, 1.19248806e-08f};
    const float sinv[4] = {0.0f, 1.0f, -8.74227766e-08f, -1.0f};
#pragma unroll
    for (int p = 0; p < 4; ++p) {
        int wcol = wbase + px0 + p;
        float a0 = acc[p][0], a1 = acc[p][1];
        float a2 = acc[p][2], a3 = acc[p][3];
        float best = a0; int bi = 0;
        if (a1 > best) { best = a1; bi = 1; }
        if (a2 > best) { best = a2; bi = 2; }
        if (a3 > best) { best = a3; bi = 3; }
        size_t o = ((size_t)(b * COUT_ + oc) * H_ + h) * W_ + wcol;
        out[o]              = best;
        out[o + OUTSZ_]     = cosv[bi];
        out[o + 2 * OUTSZ_] = sinv[bi];
    }
}

extern "C" void kernel_launch(void* const* d_in, const int* in_sizes, int n_in,
                              void* d_out, int out_size, void* d_ws, size_t ws_size,
                              hipStream_t stream)
{
    const float* f  = (const float*)d_in[0];
    const float* r0 = (const float*)d_in[1];
    const float* r1 = (const float*)d_in[2];
    const float* w  = (const float*)d_in[3];
    const float* wr = (const float*)d_in[4];
    float* out = (float*)d_out;
    float* tab = (float*)d_ws;    // 294912 B

    build_wtab<<<dim3(36), dim3(256), 0, stream>>>(w, wr, tab);
    orient_conv_kernel<<<dim3(B_ * H_ * 4), dim3(256), 0, stream>>>(
        f, r0, r1, tab, out);
}

// Round 10
// 298.591 us; speedup vs baseline: 3.6449x; 1.0536x over previous
//
#include <hip/hip_runtime.h>

// Orient_Conv: 3x3 orientation-gated conv, 4 orientations + per-pixel argmax.
// B=4, CIN=COUT=32, H=W=128, pad=1.
//
// Gate identity (C=cos(wr), S=sin(wr), r0=cos(th), r1=sin(th)):
//   u = C*r0+S*r1, v = C*r1-S*r0
//   gates: o0=relu(u), o1=relu(v), o2=relu(-u)=relu(u)-u, o3=relu(v)-v
// Rotated weights at tap (i,j): w0=w[i][j], w1=w[2-j][i], w2=w[2-i][2-j],
//   w3=w[j][2-i].
//
// R9 = R5 core with 8 px/thread (halves per-element LDS insts, weight loads,
// staging, barriers, wave count; VALU floor 123 us unchanged) and NO
// launch_bounds min-waves arg: every prior round the compiler capped VGPR at
// 64 (spilling GBs when forced — R4/R7); this kernel needs ~105 VGPR and
// must be allowed to take them. Block 256 = 32oc x 8pxg (64-px tile),
// grid 1024, NC=4 channels per barrier-pair with R5's register prefetch.

#define B_    4
#define CIN_  32
#define COUT_ 32
#define H_    128
#define W_    128
#define HW_   (H_ * W_)
#define OUTSZ_ (B_ * COUT_ * H_ * W_)

// tab layout: [cc][tap][oc][8] = {C,S,w0,w1,w2,w3,0,0}; 294912 B
__global__ __launch_bounds__(256)
void build_wtab(const float* __restrict__ w, const float* __restrict__ wr,
                float* __restrict__ tab)
{
    int idx = blockIdx.x * 256 + threadIdx.x;   // ((cc*9+tap)<<5)|oc
    if (idx >= CIN_ * 9 * COUT_) return;        // 9216
    int oc  = idx & 31;
    int t2  = idx >> 5;
    int tap = t2 % 9;
    int cc  = t2 / 9;
    int i = tap / 3, j = tap - i * 3;
    int base = (oc * CIN_ + cc) * 9;
    float w0 = w[base + i * 3 + j];
    float w1 = w[base + (2 - j) * 3 + i];
    float w2 = w[base + (2 - i) * 3 + (2 - j)];
    float w3 = w[base + j * 3 + (2 - i)];
    float S, C;
    sincosf(wr[base + i * 3 + j], &S, &C);
    float* dst = tab + (size_t)idx * 8;
    dst[0] = C;  dst[1] = S;
    dst[2] = w0; dst[3] = w1;
    dst[4] = w2; dst[5] = w3;
    dst[6] = 0.0f; dst[7] = 0.0f;
}

#define NC_    4                      // channels staged per barrier-pair
#define NG_    (CIN_ / NC_)           // 8 groups
#define RSTR_  68                     // col stride (66 used)
#define CLSTR_ (3 * RSTR_)            // 204 floats per staged channel
#define USED_  (NC_ * CLSTR_)         // 816 slots per plane
#define ASZ_   (USED_ + 4)            // plane array size (pad for dead writes)

__global__ __launch_bounds__(256)
void orient_conv_kernel(const float* __restrict__ f,
                        const float* __restrict__ r0,
                        const float* __restrict__ r1,
                        const float* __restrict__ tab,
                        float* __restrict__ out)
{
    __shared__ float sF[ASZ_], sR0[ASZ_], sR1[ASZ_];   // ~9.8 KB total

    const int tid   = threadIdx.x;
    const int oc    = tid & 31;
    const int pxg   = tid >> 5;            // 0..7
    const int px0   = pxg << 3;            // 8 px per thread (0..56)
    const int bid   = blockIdx.x;          // 0..1023
    const int b     = bid >> 8;
    const int rem   = bid & 255;
    const int h     = rem >> 1;            // 0..127
    const int wbase = (rem & 1) << 6;      // 0 or 64

    // ---- staging descriptors: rounds 0..2 always valid, round 3 tid<48 ----
    int      goff[4], sidx[4];
    unsigned msk[4];
#pragma unroll
    for (int k = 0; k < 4; ++k) {
        int s = tid + (k << 8);
        if (s < USED_) {
            int cl  = s / CLSTR_;
            int r2  = s - cl * CLSTR_;
            int row = r2 / RSTR_;
            int col = r2 - row * RSTR_;     // 0..67 (66,67 = pad)
            int gh = h + row - 1;
            int gw = wbase + col - 1;
            bool ok = (col < 66) & ((unsigned)gh < (unsigned)H_) &
                      ((unsigned)gw < (unsigned)W_);
            goff[k] = ok ? (cl * HW_ + gh * W_ + gw) : 0;
            msk[k]  = ok ? 0xFFFFFFFFu : 0u;
            sidx[k] = s;
        } else { goff[k] = 0; msk[k] = 0u; sidx[k] = USED_; }
    }
    const bool have3 = (tid + 768) < USED_;   // tid < 48
    const int chanBase = b * (CIN_ * HW_);

    float acc[8][4];                       // [px][orient]
#pragma unroll
    for (int p = 0; p < 8; ++p)
#pragma unroll
        for (int o = 0; o < 4; ++o) acc[p][o] = 0.0f;

    // ---- prefetch group 0 ----
    float tF[4], tA[4], tB[4];
    {
        const float* fb = f  + chanBase;
        const float* ab = r0 + chanBase;
        const float* bb = r1 + chanBase;
#pragma unroll
        for (int k = 0; k < 3; ++k) {
            tF[k] = fb[goff[k]]; tA[k] = ab[goff[k]]; tB[k] = bb[goff[k]];
        }
        if (have3) { tF[3] = fb[goff[3]]; tA[3] = ab[goff[3]]; tB[3] = bb[goff[3]]; }
    }

#pragma unroll 1
    for (int g = 0; g < NG_; ++g) {
        __syncthreads();   // all waves done reading LDS of group g-1
#pragma unroll
        for (int k = 0; k < 3; ++k) {
            sF [sidx[k]] = __uint_as_float(__float_as_uint(tF[k]) & msk[k]);
            sR0[sidx[k]] = __uint_as_float(__float_as_uint(tA[k]) & msk[k]);
            sR1[sidx[k]] = __uint_as_float(__float_as_uint(tB[k]) & msk[k]);
        }
        if (have3) {
            sF [sidx[3]] = __uint_as_float(__float_as_uint(tF[3]) & msk[3]);
            sR0[sidx[3]] = __uint_as_float(__float_as_uint(tA[3]) & msk[3]);
            sR1[sidx[3]] = __uint_as_float(__float_as_uint(tB[3]) & msk[3]);
        }
        __syncthreads();

        // ---- prefetch group g+1 (in flight during compute below) ----
        if (g + 1 < NG_) {
            const int gb = chanBase + (g + 1) * (NC_ * HW_);
            const float* fb = f  + gb;
            const float* ab = r0 + gb;
            const float* bb = r1 + gb;
#pragma unroll
            for (int k = 0; k < 3; ++k) {
                tF[k] = fb[goff[k]]; tA[k] = ab[goff[k]]; tB[k] = bb[goff[k]];
            }
            if (have3) { tF[3] = fb[goff[3]]; tA[3] = ab[goff[3]]; tB[3] = bb[goff[3]]; }
        }

        // ---- compute the NC_ staged channels ----
#pragma unroll 1
        for (int cl = 0; cl < NC_; ++cl) {
            const int cc = g * NC_ + cl;
            // two imm-offset anchors (taps 2 and 6): all 18 weight loads in
            // signed-13-bit global imm offsets
            const float* wb0 = tab + (size_t)(((cc * 9 + 2) << 5) | oc) * 8;
            const float* wb1 = wb0 + 4 * 256;
#pragma unroll
            for (int i = 0; i < 3; ++i) {
                const int bi = cl * CLSTR_ + i * RSTR_ + px0;
                float4 Fa = *reinterpret_cast<const float4*>(&sF [bi]);
                float4 Fb = *reinterpret_cast<const float4*>(&sF [bi + 4]);
                float2 Fc = *reinterpret_cast<const float2*>(&sF [bi + 8]);
                float4 Aa = *reinterpret_cast<const float4*>(&sR0[bi]);
                float4 Ab = *reinterpret_cast<const float4*>(&sR0[bi + 4]);
                float2 Ac = *reinterpret_cast<const float2*>(&sR0[bi + 8]);
                float4 Ba = *reinterpret_cast<const float4*>(&sR1[bi]);
                float4 Bb = *reinterpret_cast<const float4*>(&sR1[bi + 4]);
                float2 Bc = *reinterpret_cast<const float2*>(&sR1[bi + 8]);
                const float fin[10]  = {Fa.x, Fa.y, Fa.z, Fa.w, Fb.x, Fb.y,
                                        Fb.z, Fb.w, Fc.x, Fc.y};
                const float ain[10]  = {Aa.x, Aa.y, Aa.z, Aa.w, Ab.x, Ab.y,
                                        Ab.z, Ab.w, Ac.x, Ac.y};
                const float bin_[10] = {Ba.x, Ba.y, Ba.z, Ba.w, Bb.x, Bb.y,
                                        Bb.z, Bb.w, Bc.x, Bc.y};
#pragma unroll
                for (int j = 0; j < 3; ++j) {
                    const int tap = i * 3 + j;
                    const float* wp = (tap < 5) ? (wb0 + (tap - 2) * 256)
                                                : (wb1 + (tap - 6) * 256);
                    float4 W4 = *reinterpret_cast<const float4*>(wp);
                    float2 W2 = *reinterpret_cast<const float2*>(wp + 4);
                    const float C  = W4.x, S  = W4.y;
                    const float w0 = W4.z, w1 = W4.w;
                    const float w2 = W2.x, w3 = W2.y;
#pragma unroll
                    for (int p = 0; p < 8; ++p) {
                        const float fv  = fin [p + j];
                        const float r0v = ain [p + j];
                        const float r1v = bin_[p + j];
                        float u  = fmaf(C, r0v, S * r1v);
                        float vv = fmaf(C, r1v, -(S * r0v));
                        float g0 = fmaxf(u,  0.0f);
                        float g1 = fmaxf(vv, 0.0f);
                        float g2 = g0 - u;     // relu(-u), exact
                        float g3 = g1 - vv;    // relu(-v), exact
                        acc[p][0] = fmaf(fv * g0, w0, acc[p][0]);
                        acc[p][1] = fmaf(fv * g1, w1, acc[p][1]);
                        acc[p][2] = fmaf(fv * g2, w2, acc[p][2]);
                        acc[p][3] = fmaf(fv * g3, w3, acc[p][3]);
                    }
                }
            }
        }
    }

    // ---- epilogue: max/argmax over orientations (first-max tie-break) ----
    const float cosv[4] = {1.0f, -4.37113883e-08f, -1.0f, 1.19248806e-08f};
    const float sinv[4] = {0.0f, 1.0f, -8.74227766e-08f, -1.0f};
#pragma unroll
    for (int p = 0; p < 8; ++p) {
        int wcol = wbase + px0 + p;
        float a0 = acc[p][0], a1 = acc[p][1];
        float a2 = acc[p][2], a3 = acc[p][3];
        float best = a0; int bi = 0;
        if (a1 > best) { best = a1; bi = 1; }
        if (a2 > best) { best = a2; bi = 2; }
        if (a3 > best) { best = a3; bi = 3; }
        size_t o = ((size_t)(b * COUT_ + oc) * H_ + h) * W_ + wcol;
        out[o]              = best;
        out[o + OUTSZ_]     = cosv[bi];
        out[o + 2 * OUTSZ_] = sinv[bi];
    }
}

extern "C" void kernel_launch(void* const* d_in, const int* in_sizes, int n_in,
                              void* d_out, int out_size, void* d_ws, size_t ws_size,
                              hipStream_t stream)
{
    const float* f  = (const float*)d_in[0];
    const float* r0 = (const float*)d_in[1];
    const float* r1 = (const float*)d_in[2];
    const float* w  = (const float*)d_in[3];
    const float* wr = (const float*)d_in[4];
    float* out = (float*)d_out;
    float* tab = (float*)d_ws;    // 294912 B

    build_wtab<<<dim3(36), dim3(256), 0, stream>>>(w, wr, tab);
    orient_conv_kernel<<<dim3(B_ * H_ * 2), dim3(256), 0, stream>>>(
        f, r0, r1, tab, out);
}

// Round 11
// 288.734 us; speedup vs baseline: 3.7693x; 1.0341x over previous
//
#include <hip/hip_runtime.h>

// Orient_Conv: 3x3 orientation-gated conv, 4 orientations + per-pixel argmax.
// B=4, CIN=COUT=32, H=W=128, pad=1.
//
// Gate identity (C=cos(wr), S=sin(wr), r0=cos(th), r1=sin(th)):
//   u = C*r0+S*r1, vv = C*r1-S*r0
//   gates: o0=relu(u), o1=relu(vv), o2=relu(-u), o3=relu(-vv)
//   products: t0=f*relu(u), t1=f*relu(vv), t2 = t0 - f*u (=f*relu(-u)),
//             t3 = t1 - f*vv  -> 14-op core, packed 2 px/v2f = 8 VALU/elem.
// Rotated weights at tap (i,j): w0=w[i][j], w1=w[2-j][i], w2=w[2-i][2-j],
//   w3=w[j][2-i].
//
// R10 = R3's mov-free interleaved-pair LDS packing ({col,col+32} pairs; 2
// ds_read_b128 -> 4 ready v2f pairs, fP[q+j] free) + R5's NC=8 register-
// prefetch pipeline + 14-op packed core. Rationale: R5/R8/R9 all plateau at
// 263-272 us with scalar VALU busy 174-190 us ~= the measured achievable
// fp32 issue rate (m07: 103 TF); R3 proved packing cuts busy (166 us).
// Weight table [cc][tap][oc][8] (coalesced 1KB wave loads), 2 imm anchors.

typedef float v2f __attribute__((ext_vector_type(2)));

#define B_    4
#define CIN_  32
#define COUT_ 32
#define H_    128
#define W_    128
#define HW_   (H_ * W_)
#define OUTSZ_ (B_ * COUT_ * H_ * W_)

// tab layout: [cc][tap][oc][8] = {C,S,w0,w1,w2,w3,0,0}; 294912 B
__global__ __launch_bounds__(256)
void build_wtab(const float* __restrict__ w, const float* __restrict__ wr,
                float* __restrict__ tab)
{
    int idx = blockIdx.x * 256 + threadIdx.x;   // ((cc*9+tap)<<5)|oc
    if (idx >= CIN_ * 9 * COUT_) return;        // 9216
    int oc  = idx & 31;
    int t2  = idx >> 5;
    int tap = t2 % 9;
    int cc  = t2 / 9;
    int i = tap / 3, j = tap - i * 3;
    int base = (oc * CIN_ + cc) * 9;
    float w0 = w[base + i * 3 + j];
    float w1 = w[base + (2 - j) * 3 + i];
    float w2 = w[base + (2 - i) * 3 + (2 - j)];
    float w3 = w[base + j * 3 + (2 - i)];
    float S, C;
    sincosf(wr[base + i * 3 + j], &S, &C);
    float* dst = tab + (size_t)idx * 8;
    dst[0] = C;  dst[1] = S;
    dst[2] = w0; dst[3] = w1;
    dst[4] = w2; dst[5] = w3;
    dst[6] = 0.0f; dst[7] = 0.0f;
}

#define NC_    8                      // channels staged per barrier-pair
#define NG_    (CIN_ / NC_)           // 4 groups
#define ROWF_  68                     // floats per row = 34 pairs x 2
#define CLSTR_ (3 * ROWF_)            // 204 floats per staged channel
#define USED_  (NC_ * CLSTR_)         // 1632 slots per plane
#define PLANE_ 1636                   // plane stride (pad; 1636%32=4)

__global__ __launch_bounds__(512, 4)
void orient_conv_kernel(const float* __restrict__ f,
                        const float* __restrict__ r0,
                        const float* __restrict__ r1,
                        const float* __restrict__ tab,
                        float* __restrict__ out)
{
    // planes: 0=f, PLANE_=r0, 2*PLANE_=r1. Within plane:
    // [cl(8)][row(3)][pairslot(68)] ; pairslot = c01*2 + s holds col c01+32*s
    __shared__ float sm[3 * PLANE_];   // 19632 B

    const int tid   = threadIdx.x;
    const int oc    = tid & 31;
    const int pxg   = tid >> 5;            // 0..15
    const int p     = pxg << 1;            // even pair index 0..30
    const int bid   = blockIdx.x;          // 0..1023
    const int b     = bid >> 8;
    const int rem   = bid & 255;
    const int h     = rem >> 1;
    const int wbase = (rem & 1) << 6;      // 0 or 64

    // ---- staging descriptors: rounds 0..2 always valid, round 3 tid<96 ----
    int      goff[4], sidx[4];
    unsigned msk[4];
#pragma unroll
    for (int k = 0; k < 4; ++k) {
        int s = tid + (k << 9);
        if (s < USED_) {
            int cl  = s / CLSTR_;
            int r2  = s - cl * CLSTR_;
            int row = r2 / ROWF_;
            int q2  = r2 - row * ROWF_;     // 0..67
            int col = (q2 >> 1) + ((q2 & 1) << 5);   // c01 + 32*s -> 0..65
            int gh = h + row - 1;
            int gw = wbase + col - 1;
            bool ok = ((unsigned)gh < (unsigned)H_) & ((unsigned)gw < (unsigned)W_);
            goff[k] = ok ? (cl * HW_ + gh * W_ + gw) : 0;
            msk[k]  = ok ? 0xFFFFFFFFu : 0u;
            sidx[k] = s;
        } else { goff[k] = 0; msk[k] = 0u; sidx[k] = USED_; }  // pad slot
    }
    const bool have3 = (tid + 1536) < USED_;   // tid < 96
    const int chanBase = b * (CIN_ * HW_);

    v2f acc[2][4];                     // [pair q][orient]; elems = px, px+32
#pragma unroll
    for (int q = 0; q < 2; ++q)
#pragma unroll
        for (int o = 0; o < 4; ++o) acc[q][o] = (v2f)(0.0f);

    // ---- prefetch group 0 ----
    float tF[4], tA[4], tB[4];
    {
        const float* fb = f  + chanBase;
        const float* ab = r0 + chanBase;
        const float* bb = r1 + chanBase;
#pragma unroll
        for (int k = 0; k < 3; ++k) {
            tF[k] = fb[goff[k]]; tA[k] = ab[goff[k]]; tB[k] = bb[goff[k]];
        }
        if (have3) { tF[3] = fb[goff[3]]; tA[3] = ab[goff[3]]; tB[3] = bb[goff[3]]; }
    }

#pragma unroll 1
    for (int g = 0; g < NG_; ++g) {
        __syncthreads();   // all waves done reading LDS of group g-1
#pragma unroll
        for (int k = 0; k < 3; ++k) {
            sm[             sidx[k]] = __uint_as_float(__float_as_uint(tF[k]) & msk[k]);
            sm[PLANE_     + sidx[k]] = __uint_as_float(__float_as_uint(tA[k]) & msk[k]);
            sm[2 * PLANE_ + sidx[k]] = __uint_as_float(__float_as_uint(tB[k]) & msk[k]);
        }
        if (have3) {
            sm[             sidx[3]] = __uint_as_float(__float_as_uint(tF[3]) & msk[3]);
            sm[PLANE_     + sidx[3]] = __uint_as_float(__float_as_uint(tA[3]) & msk[3]);
            sm[2 * PLANE_ + sidx[3]] = __uint_as_float(__float_as_uint(tB[3]) & msk[3]);
        }
        __syncthreads();

        // ---- prefetch group g+1 (in flight during compute below) ----
        if (g + 1 < NG_) {
            const int gb = chanBase + (g + 1) * (NC_ * HW_);
            const float* fb = f  + gb;
            const float* ab = r0 + gb;
            const float* bb = r1 + gb;
#pragma unroll
            for (int k = 0; k < 3; ++k) {
                tF[k] = fb[goff[k]]; tA[k] = ab[goff[k]]; tB[k] = bb[goff[k]];
            }
            if (have3) { tF[3] = fb[goff[3]]; tA[3] = ab[goff[3]]; tB[3] = bb[goff[3]]; }
        }

        // ---- compute the NC_ staged channels ----
#pragma unroll 1
        for (int cl = 0; cl < NC_; ++cl) {
            const int cc = g * NC_ + cl;
            // imm-offset anchors (taps 2 and 6): all 18 weight loads within
            // signed-13-bit global imm offsets
            const float* wb0 = tab + (size_t)(((cc * 9 + 2) << 5) | oc) * 8;
            const float* wb1 = wb0 + 4 * 256;
#pragma unroll
            for (int i = 0; i < 3; ++i) {
                const int bi = cl * CLSTR_ + i * ROWF_ + (p << 1);
                float4 fA = *reinterpret_cast<const float4*>(&sm[bi]);
                float4 fB = *reinterpret_cast<const float4*>(&sm[bi + 4]);
                float4 aA = *reinterpret_cast<const float4*>(&sm[PLANE_ + bi]);
                float4 aB = *reinterpret_cast<const float4*>(&sm[PLANE_ + bi + 4]);
                float4 bA = *reinterpret_cast<const float4*>(&sm[2 * PLANE_ + bi]);
                float4 bB = *reinterpret_cast<const float4*>(&sm[2 * PLANE_ + bi + 4]);
                v2f fP[4]  = {{fA.x, fA.y}, {fA.z, fA.w}, {fB.x, fB.y}, {fB.z, fB.w}};
                v2f aP[4]  = {{aA.x, aA.y}, {aA.z, aA.w}, {aB.x, aB.y}, {aB.z, aB.w}};
                v2f bP[4]  = {{bA.x, bA.y}, {bA.z, bA.w}, {bB.x, bB.y}, {bB.z, bB.w}};
#pragma unroll
                for (int j = 0; j < 3; ++j) {
                    const int tap = i * 3 + j;
                    const float* wp = (tap < 5) ? (wb0 + (tap - 2) * 256)
                                                : (wb1 + (tap - 6) * 256);
                    float4 W4 = *reinterpret_cast<const float4*>(wp);
                    float2 W2 = *reinterpret_cast<const float2*>(wp + 4);
                    v2f C2  = {W4.x, W4.x};
                    v2f S2  = {W4.y, W4.y};
                    v2f w02 = {W4.z, W4.z};
                    v2f w12 = {W4.w, W4.w};
                    v2f w22 = {W2.x, W2.x};
                    v2f w32 = {W2.y, W2.y};
#pragma unroll
                    for (int q = 0; q < 2; ++q) {
                        v2f fv  = fP[q + j];
                        v2f r0v = aP[q + j];
                        v2f r1v = bP[q + j];
                        v2f m1 = S2 * r1v;
                        v2f u  = __builtin_elementwise_fma(C2, r0v, m1);
                        v2f m2 = S2 * r0v;
                        v2f vv = __builtin_elementwise_fma(C2, r1v, -m2);
                        v2f g0 = __builtin_elementwise_max(u,  (v2f)(0.0f));
                        v2f g1 = __builtin_elementwise_max(vv, (v2f)(0.0f));
                        v2f t0 = fv * g0;
                        v2f t1 = fv * g1;
                        v2f t2 = __builtin_elementwise_fma(fv, -u,  t0);  // f*relu(-u)
                        v2f t3 = __builtin_elementwise_fma(fv, -vv, t1);  // f*relu(-vv)
                        acc[q][0] = __builtin_elementwise_fma(t0, w02, acc[q][0]);
                        acc[q][1] = __builtin_elementwise_fma(t1, w12, acc[q][1]);
                        acc[q][2] = __builtin_elementwise_fma(t2, w22, acc[q][2]);
                        acc[q][3] = __builtin_elementwise_fma(t3, w32, acc[q][3]);
                    }
                }
            }
        }
    }

    // ---- epilogue: max/argmax over orientations (first-max tie-break) ----
    const float cosv[4] = {1.0f, -4.37113883e-08f, -1.0f, 1.19248806e-08f};
    const float sinv[4] = {0.0f, 1.0f, -8.74227766e-08f, -1.0f};
#pragma unroll
    for (int q = 0; q < 2; ++q) {
#pragma unroll
        for (int k = 0; k < 2; ++k) {
            int wcol = wbase + p + q + (k << 5);
            float a0 = acc[q][0][k], a1 = acc[q][1][k];
            float a2 = acc[q][2][k], a3 = acc[q][3][k];
            float best = a0; int bi = 0;
            if (a1 > best) { best = a1; bi = 1; }
            if (a2 > best) { best = a2; bi = 2; }
            if (a3 > best) { best = a3; bi = 3; }
            size_t o = ((size_t)(b * COUT_ + oc) * H_ + h) * W_ + wcol;
            out[o]              = best;
            out[o + OUTSZ_]     = cosv[bi];
            out[o + 2 * OUTSZ_] = sinv[bi];
        }
    }
}

extern "C" void kernel_launch(void* const* d_in, const int* in_sizes, int n_in,
                              void* d_out, int out_size, void* d_ws, size_t ws_size,
                              hipStream_t stream)
{
    const float* f  = (const float*)d_in[0];
    const float* r0 = (const float*)d_in[1];
    const float* r1 = (const float*)d_in[2];
    const float* w  = (const float*)d_in[3];
    const float* wr = (const float*)d_in[4];
    float* out = (float*)d_out;
    float* tab = (float*)d_ws;    // 294912 B

    build_wtab<<<dim3(36), dim3(256), 0, stream>>>(w, wr, tab);
    orient_conv_kernel<<<dim3(B_ * H_ * 2), dim3(512), 0, stream>>>(
        f, r0, r1, tab, out);
}